// Round 1
// baseline (583.214 us; speedup 1.0000x reference)
//
#include <hip/hip_runtime.h>

// Cumulative max (prefix-max scan) along axis 2 of x:(32, 1, 1024, 1024) fp32.
// 32768 independent columns (b, w); thread t scans column t sequentially.
// Lanes within a wave cover consecutive w -> coalesced 256B/wave per h step.
// #pragma unroll 32 lets the compiler keep ~32 loads in flight per wave
// (loads are independent of the running-max chain), hiding HBM latency at
// only 2 waves/CU.

constexpr int H = 1024;
constexpr int W = 1024;
constexpr int NCOL = 32 * W;  // B * W

__global__ __launch_bounds__(64) void cummax_col_kernel(const float* __restrict__ x,
                                                        float* __restrict__ out) {
    const int t = blockIdx.x * 64 + threadIdx.x;   // column id, 0..NCOL-1
    const int b = t >> 10;                          // t / W
    const int w = t & (W - 1);                      // t % W
    const size_t base = (size_t)b * (size_t)(H * W) + (size_t)w;
    const float* xp = x + base;
    float* op = out + base;

    float m = -__builtin_inff();
#pragma unroll 32
    for (int h = 0; h < H; ++h) {
        float v = xp[(size_t)h * W];
        m = fmaxf(m, v);
        op[(size_t)h * W] = m;
    }
}

extern "C" void kernel_launch(void* const* d_in, const int* in_sizes, int n_in,
                              void* d_out, int out_size, void* d_ws, size_t ws_size,
                              hipStream_t stream) {
    const float* x = (const float*)d_in[0];
    float* out = (float*)d_out;
    cummax_col_kernel<<<NCOL / 64, 64, 0, stream>>>(x, out);
}

// Round 2
// 262.459 us; speedup vs baseline: 2.2221x; 2.2221x over previous
//
#include <hip/hip_runtime.h>

// Cumulative max along axis 2 of x:(32, 1, 1024, 1024) fp32, as a 3-phase
// segmented scan to break the serial-H latency chain (round 1 was
// latency-bound: 2 waves/CU, ~1000 cy per h-step).
//
// Decomposition: column-group cg = (b, w/4) handles 4 consecutive w via
// float4 (8192 cgs). H split into S=32 segments of R=32 rows.
//   K1: thread (cg, s) -> max of its 32 rows (independent loads), ws[s][cg]
//   K2: thread (cg)    -> in-place exclusive prefix-max over s of ws[s][cg]
//   K3: thread (cg, s) -> carry = ws[s][cg]; rescan rows, write out
// 262144 threads in K1/K3 = 4096 waves = 16 waves/CU; loads coalesced
// (consecutive lanes = consecutive cg = contiguous 16B) -> 1KiB/wave/instr.
// ws usage: 32 * 8192 * 16 B = 4 MiB.

constexpr int B = 32;
constexpr int H = 1024;
constexpr int W = 1024;
constexpr int S = 32;              // segments per column
constexpr int R = H / S;           // rows per segment (32)
constexpr int NCG = B * (W / 4);   // 8192 column groups (float4 wide)
constexpr int ROW4 = W / 4;        // 256 float4 per row

__device__ __forceinline__ float4 max4(float4 a, float4 b) {
    return make_float4(fmaxf(a.x, b.x), fmaxf(a.y, b.y),
                       fmaxf(a.z, b.z), fmaxf(a.w, b.w));
}

__global__ __launch_bounds__(256, 4) void segmax_kernel(const float* __restrict__ x,
                                                        float4* __restrict__ ws4) {
    const int t = blockIdx.x * 256 + threadIdx.x;   // 0..NCG*S-1
    const int cg = t & (NCG - 1);
    const int s = t >> 13;                          // t / NCG
    const int b = cg >> 8;                          // cg / ROW4
    const int wg = cg & (ROW4 - 1);
    const float4* xp = (const float4*)x + (size_t)b * (H * ROW4)
                       + (size_t)(s * R) * ROW4 + wg;
    const float ninf = -__builtin_inff();
    float4 m = make_float4(ninf, ninf, ninf, ninf);
#pragma unroll
    for (int r = 0; r < R; ++r) {
        m = max4(m, xp[(size_t)r * ROW4]);
    }
    ws4[(size_t)s * NCG + cg] = m;
}

__global__ __launch_bounds__(256) void prefix_kernel(float4* __restrict__ ws4) {
    const int cg = blockIdx.x * 256 + threadIdx.x;  // 0..NCG-1
    const float ninf = -__builtin_inff();
    float4 run = make_float4(ninf, ninf, ninf, ninf);
#pragma unroll
    for (int s = 0; s < S; ++s) {
        float4 v = ws4[(size_t)s * NCG + cg];
        ws4[(size_t)s * NCG + cg] = run;            // exclusive prefix
        run = max4(run, v);
    }
}

__global__ __launch_bounds__(256, 4) void apply_kernel(const float* __restrict__ x,
                                                       float* __restrict__ out,
                                                       const float4* __restrict__ ws4) {
    const int t = blockIdx.x * 256 + threadIdx.x;
    const int cg = t & (NCG - 1);
    const int s = t >> 13;
    const int b = cg >> 8;
    const int wg = cg & (ROW4 - 1);
    const size_t base = (size_t)b * (H * ROW4) + (size_t)(s * R) * ROW4 + wg;
    const float4* xp = (const float4*)x + base;
    float4* op = (float4*)out + base;
    float4 carry = ws4[(size_t)s * NCG + cg];
#pragma unroll
    for (int r = 0; r < R; ++r) {
        carry = max4(carry, xp[(size_t)r * ROW4]);
        op[(size_t)r * ROW4] = carry;
    }
}

extern "C" void kernel_launch(void* const* d_in, const int* in_sizes, int n_in,
                              void* d_out, int out_size, void* d_ws, size_t ws_size,
                              hipStream_t stream) {
    const float* x = (const float*)d_in[0];
    float* out = (float*)d_out;
    float4* ws4 = (float4*)d_ws;

    segmax_kernel<<<(NCG * S) / 256, 256, 0, stream>>>(x, ws4);
    prefix_kernel<<<NCG / 256, 256, 0, stream>>>(ws4);
    apply_kernel<<<(NCG * S) / 256, 256, 0, stream>>>(x, out, ws4);
}

// Round 4
// 255.138 us; speedup vs baseline: 2.2859x; 1.0287x over previous
//
#include <hip/hip_runtime.h>

// Cumulative max along axis 2 of x:(32, 1, 1024, 1024) fp32 — 3-phase
// segmented scan. Round-2 post-mortem: 3 kernels summed ~106us vs ~65us
// floor; fixes: (1) S=64 segments -> 8192 waves = 32 waves/CU (was 16)
// for 2x memory-level parallelism; (2) K2 scalar-per-column (512 waves,
// was 128); (3) K3 nontemporal output stores so the 128 MiB of out-writes
// don't evict x from L2/L3 before its second read (x is L3-resident after
// K1: 128 MiB < 256 MiB Infinity Cache).
// Round-3 fix: __builtin_nontemporal_store needs a native vector type,
// not HIP_vector_type -> store via ext_vector_type(4) float.

constexpr int B = 32;
constexpr int H = 1024;
constexpr int W = 1024;
constexpr int S = 64;              // segments per column
constexpr int R = H / S;           // 16 rows per segment
constexpr int NCG = B * (W / 4);   // 8192 column groups (float4 wide)
constexpr int ROW4 = W / 4;        // 256 float4 per row
constexpr int NCOL = B * W;        // 32768 scalar columns

typedef float floatx4 __attribute__((ext_vector_type(4)));

__device__ __forceinline__ float4 max4(float4 a, float4 b) {
    return make_float4(fmaxf(a.x, b.x), fmaxf(a.y, b.y),
                       fmaxf(a.z, b.z), fmaxf(a.w, b.w));
}

// K1: thread (cg, s) -> max over its R rows (16 independent float4 loads).
__global__ __launch_bounds__(256) void segmax_kernel(const float* __restrict__ x,
                                                     float4* __restrict__ ws4) {
    const int t = blockIdx.x * 256 + threadIdx.x;   // 0..NCG*S-1
    const int cg = t & (NCG - 1);
    const int s = t >> 13;                          // t / NCG
    const int b = cg >> 8;                          // cg / ROW4
    const int wg = cg & (ROW4 - 1);
    const float4* xp = (const float4*)x + (size_t)b * (H * ROW4)
                       + (size_t)(s * R) * ROW4 + wg;
    const float ninf = -__builtin_inff();
    float4 m = make_float4(ninf, ninf, ninf, ninf);
#pragma unroll
    for (int r = 0; r < R; ++r) {
        m = max4(m, xp[(size_t)r * ROW4]);
    }
    ws4[(size_t)s * NCG + cg] = m;
}

// K2: exclusive prefix-max over s, one thread per scalar column (coalesced:
// consecutive threads -> consecutive addresses; ws viewed as [S][NCOL] floats).
__global__ __launch_bounds__(256) void prefix_kernel(float* __restrict__ wsf) {
    const int t = blockIdx.x * 256 + threadIdx.x;   // 0..NCOL-1
    float run = -__builtin_inff();
#pragma unroll
    for (int s = 0; s < S; ++s) {
        const size_t i = (size_t)s * NCOL + t;
        float v = wsf[i];
        wsf[i] = run;                               // exclusive prefix
        run = fmaxf(run, v);
    }
}

// K3: carry-in from ws, rescan R rows (x re-read is L2/L3-warm), nt stores.
__global__ __launch_bounds__(256) void apply_kernel(const float* __restrict__ x,
                                                    float* __restrict__ out,
                                                    const float4* __restrict__ ws4) {
    const int t = blockIdx.x * 256 + threadIdx.x;
    const int cg = t & (NCG - 1);
    const int s = t >> 13;
    const int b = cg >> 8;
    const int wg = cg & (ROW4 - 1);
    const size_t base = (size_t)b * (H * ROW4) + (size_t)(s * R) * ROW4 + wg;
    const float4* xp = (const float4*)x + base;
    floatx4* op = (floatx4*)out + base;
    float4 carry = ws4[(size_t)s * NCG + cg];
#pragma unroll
    for (int r = 0; r < R; ++r) {
        carry = max4(carry, xp[(size_t)r * ROW4]);
        floatx4 cv = {carry.x, carry.y, carry.z, carry.w};
        __builtin_nontemporal_store(cv, op + (size_t)r * ROW4);
    }
}

extern "C" void kernel_launch(void* const* d_in, const int* in_sizes, int n_in,
                              void* d_out, int out_size, void* d_ws, size_t ws_size,
                              hipStream_t stream) {
    const float* x = (const float*)d_in[0];
    float* out = (float*)d_out;

    segmax_kernel<<<(NCG * S) / 256, 256, 0, stream>>>(x, (float4*)d_ws);
    prefix_kernel<<<NCOL / 256, 256, 0, stream>>>((float*)d_ws);
    apply_kernel<<<(NCG * S) / 256, 256, 0, stream>>>(x, out, (const float4*)d_ws);
}